// Round 1
// baseline (1542.968 us; speedup 1.0000x reference)
//
#include <hip/hip_runtime.h>
#include <math.h>

#define N_FFTC    1023
#define NFREQ     512
#define NBANDS    10
#define NPATH     32768
#define NSURF     16
#define NDIR      128
#define RIR_LEN   96000
#define FILT_LEN  1023
#define TWO_PI_D  6.283185307179586476925286766559

// ---- ws layout (bytes, all 256-aligned) ----
#define WS_W      0UL            // f32 [1024][1024]  (cols 0..1022 valid)
#define WS_RIR    4194304UL      // f32 [8][96000]
#define WS_TWC    7266304UL      // dbl [1023]
#define WS_TWS    7274496UL      // dbl [1023]
#define WS_LOGR   7282688UL      // f32 [16][10]
#define WS_SIGD   7283712UL      // f32 [128][10]
#define WS_PST    7288832UL      // f32 [10][512]
#define WS_PDT    7309312UL      // f32 [10][512]
#define WS_GS     7329792UL      // dbl [10][512]
#define WS_GD     7370752UL      // dbl [10][512]
#define WS_AB     7411712UL      // f32 [chunkM][1024]

// ---------------- k0a: twiddles (fp64) + log_refl + sig_dir ----------------
__global__ void k0a_tables(const float* __restrict__ sp, const float* __restrict__ dp,
                           double* __restrict__ twc, double* __restrict__ tws,
                           float* __restrict__ logr, float* __restrict__ sigd)
{
    int idx = blockIdx.x * 256 + threadIdx.x;
    if (idx < 1023) {
        double ang = TWO_PI_D * (double)idx / 1023.0;
        twc[idx] = cos(ang);
        tws[idx] = sin(ang);
    } else if (idx >= 1024 && idx < 1024 + NSURF * NBANDS) {
        int i = idx - 1024;
        float s = 1.f / (1.f + expf(-sp[i]));
        logr[i] = logf(s <= 1e-9f ? 1e-9f : s);
    } else if (idx >= 2048 && idx < 2048 + NDIR * NBANDS) {
        int i = idx - 2048;
        sigd[i] = 1.f / (1.f + expf(-dp[i]));
    }
}

// ---------------- k0b: G[f][n] = sum_m c_m cos(2pi m n/N) * I[f][m] ----------------
__global__ void k0b_G(const float* __restrict__ SI, const float* __restrict__ DI,
                      const double* __restrict__ twc,
                      double* __restrict__ Gs, double* __restrict__ Gd)
{
    int idx = blockIdx.x * 256 + threadIdx.x;
    if (idx >= NBANDS * NFREQ) return;
    int f = idx >> 9, n = idx & 511;
    double gs = 0.0, gd = 0.0;
    for (int m = 0; m < NFREQ; ++m) {
        double c = (m == 0) ? 1.0 : 2.0;
        double t = c * twc[(m * n) % 1023];
        gs += t * (double)SI[f * NFREQ + m];
        gd += t * (double)DI[f * NFREQ + m];
    }
    Gs[idx] = gs;
    Gd[idx] = gd;
}

// ---------------- k0c: PS_T[f][k] = -(2/N) sum_{n=1}^{511} sin(2pi k n/N) G[f][n] ----------------
__global__ void k0c_PSPD(const double* __restrict__ tws,
                         const double* __restrict__ Gs, const double* __restrict__ Gd,
                         float* __restrict__ PST, float* __restrict__ PDT)
{
    int idx = blockIdx.x * 256 + threadIdx.x;
    if (idx >= NBANDS * NFREQ) return;
    int f = idx >> 9, k = idx & 511;
    double ps = 0.0, pd_ = 0.0;
    for (int n = 1; n < 512; ++n) {
        double s = tws[(k * n) % 1023];
        ps  += s * Gs[f * NFREQ + n];
        pd_ += s * Gd[f * NFREQ + n];
    }
    double sc = -2.0 / 1023.0;
    PST[idx] = (float)(sc * ps);
    PDT[idx] = (float)(sc * pd_);
}

// ---------------- k0d: W[k][t] synthesis matrix, ld=1024 ----------------
__global__ void k0d_W(const double* __restrict__ twc, const double* __restrict__ tws,
                      float* __restrict__ Wm)
{
    int idx = blockIdx.x * 256 + threadIdx.x;   // 1024*1024
    int k = idx >> 10, t = idx & 1023;
    float v = 0.f;
    if (t < 1023) {
        if (k < 512) {
            double sc = ((k == 0) ? 1.0 : 2.0) / 1023.0;
            v = (float)(sc * twc[(k * t) % 1023]);
        } else {
            int kk = k - 512;
            v = (float)((2.0 / 1023.0) * tws[(kk * t) % 1023]);
        }
    }
    Wm[idx] = v;
}

__device__ __forceinline__ float wave_sum64(float v) {
#pragma unroll
    for (int m = 1; m < 64; m <<= 1) v += __shfl_xor(v, m, 64);
    return v;
}
__device__ __forceinline__ float wave_max64(float v) {
#pragma unroll
    for (int m = 1; m < 64; m <<= 1) v = fmaxf(v, __shfl_xor(v, m, 64));
    return v;
}

// ---------------- k1: per-path a,b (gain folded). One wave per path. ----------------
__global__ __launch_bounds__(256) void k1_ab(
    const float* __restrict__ path_dirs, const float* __restrict__ fib,
    const int* __restrict__ mask, const int* __restrict__ delays,
    const float* __restrict__ logr, const float* __restrict__ sigd,
    const float* __restrict__ SI, const float* __restrict__ DI,
    const float* __restrict__ PST, const float* __restrict__ PDT,
    float* __restrict__ AB, int chunkStart, int m)
{
    int wave = threadIdx.x >> 6, lane = threadIdx.x & 63;
    int p = blockIdx.x * 4 + wave;
    if (p >= m) return;
    int pg = chunkStart + p;

    float dx = path_dirs[pg * 3 + 0], dy = path_dirs[pg * 3 + 1], dz = path_dirs[pg * 3 + 2];
    float inv = 1.f / (sqrtf(dx * dx + dy * dy + dz * dz) + 1e-9f);
    dx *= inv; dy *= inv; dz *= inv;

    int n0 = lane, n1 = lane + 64;
    float l0 = 8.f * (dx * fib[n0 * 3] + dy * fib[n0 * 3 + 1] + dz * fib[n0 * 3 + 2]);
    float l1 = 8.f * (dx * fib[n1 * 3] + dy * fib[n1 * 3 + 1] + dz * fib[n1 * 3 + 2]);
    float mx = wave_max64(fmaxf(l0, l1));
    float e0 = expf(l0 - mx), e1 = expf(l1 - mx);
    float ssum = wave_sum64(e0 + e1);
    float w0 = e0 / ssum, w1 = e1 / ssum;

    float lad[10];
#pragma unroll
    for (int f = 0; f < NBANDS; ++f) {
        float part = w0 * sigd[n0 * NBANDS + f] + w1 * sigd[n1 * NBANDS + f];
        part = wave_sum64(part);
        lad[f] = logf(part <= 1e-9f ? 1e-9f : part);
    }

    float las[10];
#pragma unroll
    for (int f = 0; f < NBANDS; ++f) las[f] = 0.f;
    const int* mrow = mask + (size_t)pg * NSURF;
#pragma unroll
    for (int s = 0; s < NSURF; ++s) {
        float mv = (float)mrow[s];
#pragma unroll
        for (int f = 0; f < NBANDS; ++f) las[f] += mv * logr[s * NBANDS + f];
    }

    int dly = delays[pg];
    float g = 1.f / fmaxf((float)dly / 48.f, 1.f);

    float* abp = AB + (size_t)p * 1024;
#pragma unroll
    for (int i = 0; i < 8; ++i) {
        int q = i * 64 + lane;
        float la = 0.f, ph = 0.f;
#pragma unroll
        for (int f = 0; f < NBANDS; ++f) {
            la += las[f] * SI[f * NFREQ + q] + lad[f] * DI[f * NFREQ + q];
            ph += las[f] * PST[f * NFREQ + q] + lad[f] * PDT[f * NFREQ + q];
        }
        float M = g * expf(la);
        float sn, cs;
        sincosf(ph, &sn, &cs);
        abp[q]       = M * cs;   // a_k
        abp[512 + q] = M * sn;   // b_k
    }
}

// ---------------- k2: fp32 GEMM [m x 1024] * [1024 x 1023] + scatter into rir ----------------
#define BM 128
#define BN 128
#define BK 16
__global__ __launch_bounds__(256) void k2_gemm_scatter(
    const float* __restrict__ AB, const float* __restrict__ Wm,
    const int* __restrict__ delays, float* __restrict__ rir,
    int chunkStart)
{
    __shared__ float As[BK][BM + 4];   // +4 pad: staging-write conflicts -> 2-way (free)
    __shared__ float Bs[BK][BN];

    // XCD-aware bijective swizzle (grid is always a multiple of 8)
    int nwg = gridDim.x;
    int cpx = nwg >> 3;
    int bid = blockIdx.x;
    int swz = (bid & 7) * cpx + (bid >> 3);
    int rowTile = swz >> 3;       // 8 N-tiles, fastest -> same row-panel stays on one XCD
    int colTile = swz & 7;
    int p0 = rowTile * BM;
    int t0 = colTile * BN;

    int tid = threadIdx.x;
    int tx = tid & 15, ty = tid >> 4;

    float acc[8][8];
#pragma unroll
    for (int i = 0; i < 8; ++i)
#pragma unroll
        for (int j = 0; j < 8; ++j) acc[i][j] = 0.f;

    for (int k0 = 0; k0 < 1024; k0 += BK) {
        __syncthreads();
#pragma unroll
        for (int jj = 0; jj < 2; ++jj) {
            int idx = tid + 256 * jj;
            // A tile: 128 rows x 16 k, transposed into As[k][row]
            int ar = idx >> 2, aks = (idx & 3) * 4;
            float4 av = *(const float4*)&AB[(size_t)(p0 + ar) * 1024 + k0 + aks];
            As[aks + 0][ar] = av.x;
            As[aks + 1][ar] = av.y;
            As[aks + 2][ar] = av.z;
            As[aks + 3][ar] = av.w;
            // B tile: 16 rows x 128 cols, direct
            int br = idx >> 5, bc = (idx & 31) * 4;
            *(float4*)&Bs[br][bc] = *(const float4*)&Wm[(size_t)(k0 + br) * 1024 + t0 + bc];
        }
        __syncthreads();
#pragma unroll
        for (int kk = 0; kk < BK; ++kk) {
            float a[8], b[8];
            *(float4*)&a[0] = *(const float4*)&As[kk][ty * 8];
            *(float4*)&a[4] = *(const float4*)&As[kk][ty * 8 + 4];
            *(float4*)&b[0] = *(const float4*)&Bs[kk][tx * 8];
            *(float4*)&b[4] = *(const float4*)&Bs[kk][tx * 8 + 4];
#pragma unroll
            for (int i = 0; i < 8; ++i)
#pragma unroll
                for (int j = 0; j < 8; ++j)
                    acc[i][j] = fmaf(a[i], b[j], acc[i][j]);
        }
    }

    // epilogue: scatter-add filt tile into rir at per-path delay
#pragma unroll
    for (int i = 0; i < 8; ++i) {
        int p = p0 + ty * 8 + i;
        int pg = chunkStart + p;
        int bi = pg >> 12;                 // path-> batch (4096 paths per b)
        int dly = delays[pg];
        float* rb = rir + (size_t)bi * RIR_LEN + dly;
#pragma unroll
        for (int j = 0; j < 8; ++j) {
            int t = t0 + tx * 8 + j;
            if (t < FILT_LEN) atomicAdd(&rb[t], acc[i][j]);
        }
    }
}

// ---------------- k3: 'same' cross-correlation with source kernel ----------------
#define SEG 1024
__global__ __launch_bounds__(256) void k3_conv(
    const float* __restrict__ rir, const float* __restrict__ kern, float* __restrict__ out)
{
    __shared__ float rs[SEG + FILT_LEN - 1 + 8];
    __shared__ float ks[FILT_LEN];
    int b = blockIdx.y;
    int t0 = blockIdx.x * SEG;
    for (int i = threadIdx.x; i < FILT_LEN; i += 256) ks[i] = kern[i];
    for (int i = threadIdx.x; i < SEG + FILT_LEN - 1 + 8; i += 256) {
        int t = t0 - 511 + i;
        rs[i] = (i < SEG + FILT_LEN - 1 && t >= 0 && t < RIR_LEN)
                    ? rir[(size_t)b * RIR_LEN + t] : 0.f;
    }
    __syncthreads();

    int base = threadIdx.x * 4;
    float a0 = 0.f, a1 = 0.f, a2 = 0.f, a3 = 0.f;
    float w0 = rs[base], w1 = rs[base + 1], w2 = rs[base + 2], w3 = rs[base + 3];
    for (int k = 0; k < FILT_LEN; ++k) {
        float kv = ks[k];
        a0 = fmaf(kv, w0, a0);
        a1 = fmaf(kv, w1, a1);
        a2 = fmaf(kv, w2, a2);
        a3 = fmaf(kv, w3, a3);
        w0 = w1; w1 = w2; w2 = w3; w3 = rs[base + k + 4];
    }
    int t = t0 + base;
    size_t ob = (size_t)b * RIR_LEN;
    if (t + 0 < RIR_LEN) out[ob + t + 0] = a0;
    if (t + 1 < RIR_LEN) out[ob + t + 1] = a1;
    if (t + 2 < RIR_LEN) out[ob + t + 2] = a2;
    if (t + 3 < RIR_LEN) out[ob + t + 3] = a3;
}

extern "C" void kernel_launch(void* const* d_in, const int* in_sizes, int n_in,
                              void* d_out, int out_size, void* d_ws, size_t ws_size,
                              hipStream_t stream)
{
    const float* surface_params = (const float*)d_in[0];
    const float* dir_params     = (const float*)d_in[1];
    const float* path_dirs      = (const float*)d_in[2];
    const float* source_kernel  = (const float*)d_in[3];
    const float* surf_interp    = (const float*)d_in[4];
    const float* dir_interp     = (const float*)d_in[5];
    const float* fib_points     = (const float*)d_in[6];
    const int*   mask           = (const int*)d_in[7];
    const int*   delays         = (const int*)d_in[8];
    float* out = (float*)d_out;
    char*  ws  = (char*)d_ws;

    float*  Wm   = (float*)(ws + WS_W);
    float*  rir  = (float*)(ws + WS_RIR);
    double* twc  = (double*)(ws + WS_TWC);
    double* tws  = (double*)(ws + WS_TWS);
    float*  logr = (float*)(ws + WS_LOGR);
    float*  sigd = (float*)(ws + WS_SIGD);
    float*  PST  = (float*)(ws + WS_PST);
    float*  PDT  = (float*)(ws + WS_PDT);
    double* Gs   = (double*)(ws + WS_GS);
    double* Gd   = (double*)(ws + WS_GD);
    float*  AB   = (float*)(ws + WS_AB);

    // adaptive chunking of the AB intermediate against ws_size
    size_t abCap = (ws_size > WS_AB) ? (ws_size - WS_AB) : 0;
    long long cm = (long long)((abCap / 4096) & ~(size_t)127);
    if (cm > NPATH) cm = NPATH;
    if (cm < 128)   cm = 128;
    int chunkM = (int)cm;

    hipMemsetAsync(rir, 0, (size_t)8 * RIR_LEN * sizeof(float), stream);

    k0a_tables<<<16, 256, 0, stream>>>(surface_params, dir_params, twc, tws, logr, sigd);
    k0b_G     <<<20, 256, 0, stream>>>(surf_interp, dir_interp, twc, Gs, Gd);
    k0c_PSPD  <<<20, 256, 0, stream>>>(tws, Gs, Gd, PST, PDT);
    k0d_W     <<<4096, 256, 0, stream>>>(twc, tws, Wm);

    for (int cs = 0; cs < NPATH; cs += chunkM) {
        int m = NPATH - cs;
        if (m > chunkM) m = chunkM;
        k1_ab<<<m / 4, 256, 0, stream>>>(path_dirs, fib_points, mask, delays,
                                         logr, sigd, surf_interp, dir_interp,
                                         PST, PDT, AB, cs, m);
        k2_gemm_scatter<<<(m / BM) * 8, 256, 0, stream>>>(AB, Wm, delays, rir, cs);
    }

    dim3 g3((RIR_LEN + SEG - 1) / SEG, 8);
    k3_conv<<<g3, 256, 0, stream>>>(rir, source_kernel, out);
}

// Round 2
// 685.232 us; speedup vs baseline: 2.2517x; 2.2517x over previous
//
#include <hip/hip_runtime.h>
#include <math.h>

#define N_FFTC    1023
#define NFREQ     512
#define NBANDS    10
#define NPATH     32768
#define NSURF     16
#define NDIR      128
#define RIR_LEN   96000
#define FILT_LEN  1023
#define TWO_PI_D  6.283185307179586476925286766559

typedef _Float16 f16x8 __attribute__((ext_vector_type(8)));
typedef float    f32x4 __attribute__((ext_vector_type(4)));

#define AS1 __attribute__((address_space(1)))
#define AS3 __attribute__((address_space(3)))
__device__ __forceinline__ void gload16(const void* g, void* l) {
    __builtin_amdgcn_global_load_lds((const AS1 void*)g, (AS3 void*)l, 16, 0, 0);
}

// ---- ws layout (bytes) ----
#define WS_RIR    0UL            // f32 [8][96000]                 3,072,000
#define WS_WT     3072000UL      // f16 [2][1024][1024] hi|lo      4,194,304
#define WS_TWC    7266304UL      // dbl [1023]
#define WS_TWS    7274496UL      // dbl [1023]
#define WS_LOGR   7282688UL      // f32 [16][10]
#define WS_SIGD   7283456UL      // f32 [128][10]
#define WS_PST    7288576UL      // f32 [10][512]
#define WS_PDT    7309056UL      // f32 [10][512]
#define WS_GS     7329536UL      // dbl [10][512]
#define WS_GD     7370496UL      // dbl [10][512]
#define WS_A      7411712UL      // f16 [chunkM][2048]  (hi 1024 | lo 1024), 4KB/path

// ---------------- k0a: twiddles (fp64) + log_refl + sig_dir ----------------
__global__ void k0a_tables(const float* __restrict__ sp, const float* __restrict__ dp,
                           double* __restrict__ twc, double* __restrict__ tws,
                           float* __restrict__ logr, float* __restrict__ sigd)
{
    int idx = blockIdx.x * 256 + threadIdx.x;
    if (idx < 1023) {
        double ang = TWO_PI_D * (double)idx / 1023.0;
        twc[idx] = cos(ang);
        tws[idx] = sin(ang);
    } else if (idx >= 1024 && idx < 1024 + NSURF * NBANDS) {
        int i = idx - 1024;
        float s = 1.f / (1.f + expf(-sp[i]));
        logr[i] = logf(s <= 1e-9f ? 1e-9f : s);
    } else if (idx >= 2048 && idx < 2048 + NDIR * NBANDS) {
        int i = idx - 2048;
        sigd[i] = 1.f / (1.f + expf(-dp[i]));
    }
}

// ---------------- k0b: G[f][n] = sum_m c_m cos(2pi m n/N) * I[f][m] ----------------
__global__ void k0b_G(const float* __restrict__ SI, const float* __restrict__ DI,
                      const double* __restrict__ twc,
                      double* __restrict__ Gs, double* __restrict__ Gd)
{
    int idx = blockIdx.x * 256 + threadIdx.x;
    if (idx >= NBANDS * NFREQ) return;
    int f = idx >> 9, n = idx & 511;
    double gs = 0.0, gd = 0.0;
    for (int m = 0; m < NFREQ; ++m) {
        double c = (m == 0) ? 1.0 : 2.0;
        double t = c * twc[(m * n) % 1023];
        gs += t * (double)SI[f * NFREQ + m];
        gd += t * (double)DI[f * NFREQ + m];
    }
    Gs[idx] = gs;
    Gd[idx] = gd;
}

// ---------------- k0c: PS_T[f][k] = -(2/N) sum_{n=1}^{511} sin(2pi k n/N) G[f][n] ----------------
__global__ void k0c_PSPD(const double* __restrict__ tws,
                         const double* __restrict__ Gs, const double* __restrict__ Gd,
                         float* __restrict__ PST, float* __restrict__ PDT)
{
    int idx = blockIdx.x * 256 + threadIdx.x;
    if (idx >= NBANDS * NFREQ) return;
    int f = idx >> 9, k = idx & 511;
    double ps = 0.0, pd_ = 0.0;
    for (int n = 1; n < 512; ++n) {
        double s = tws[(k * n) % 1023];
        ps  += s * Gs[f * NFREQ + n];
        pd_ += s * Gd[f * NFREQ + n];
    }
    double sc = -2.0 / 1023.0;
    PST[idx] = (float)(sc * ps);
    PDT[idx] = (float)(sc * pd_);
}

// ---------------- k0d: WT[t][k] synthesis matrix (transposed), f16 limbs, x2^14 ----------------
__global__ void k0d_W(const double* __restrict__ twc, const double* __restrict__ tws,
                      _Float16* __restrict__ WThi, _Float16* __restrict__ WTlo)
{
    int idx = blockIdx.x * 256 + threadIdx.x;   // 1024*1024 over [t][k]
    int t = idx >> 10, k = idx & 1023;
    double v = 0.0;
    if (t < 1023) {
        if (k < 512) v = (((k == 0) ? 1.0 : 2.0) / 1023.0) * twc[(k * t) % 1023];
        else         v = (2.0 / 1023.0) * tws[((k - 512) * t) % 1023];
    }
    float vf = (float)(v * 16384.0);
    _Float16 h = (_Float16)vf;
    WThi[idx] = h;
    WTlo[idx] = (_Float16)(vf - (float)h);
}

__device__ __forceinline__ float wave_sum64(float v) {
#pragma unroll
    for (int m = 1; m < 64; m <<= 1) v += __shfl_xor(v, m, 64);
    return v;
}
__device__ __forceinline__ float wave_max64(float v) {
#pragma unroll
    for (int m = 1; m < 64; m <<= 1) v = fmaxf(v, __shfl_xor(v, m, 64));
    return v;
}

// ---------------- k1: per-path a,b (gain + 2^14 scale folded), f16 limbs ----------------
__global__ __launch_bounds__(256) void k1_ab(
    const float* __restrict__ path_dirs, const float* __restrict__ fib,
    const int* __restrict__ mask, const int* __restrict__ delays,
    const float* __restrict__ logr, const float* __restrict__ sigd,
    const float* __restrict__ SI, const float* __restrict__ DI,
    const float* __restrict__ PST, const float* __restrict__ PDT,
    _Float16* __restrict__ A, int chunkStart, int m)
{
    int wave = threadIdx.x >> 6, lane = threadIdx.x & 63;
    int p = blockIdx.x * 4 + wave;
    if (p >= m) return;
    int pg = chunkStart + p;

    float dx = path_dirs[pg * 3 + 0], dy = path_dirs[pg * 3 + 1], dz = path_dirs[pg * 3 + 2];
    float inv = 1.f / (sqrtf(dx * dx + dy * dy + dz * dz) + 1e-9f);
    dx *= inv; dy *= inv; dz *= inv;

    int n0 = lane, n1 = lane + 64;
    float l0 = 8.f * (dx * fib[n0 * 3] + dy * fib[n0 * 3 + 1] + dz * fib[n0 * 3 + 2]);
    float l1 = 8.f * (dx * fib[n1 * 3] + dy * fib[n1 * 3 + 1] + dz * fib[n1 * 3 + 2]);
    float mx = wave_max64(fmaxf(l0, l1));
    float e0 = expf(l0 - mx), e1 = expf(l1 - mx);
    float ssum = wave_sum64(e0 + e1);
    float w0 = e0 / ssum, w1 = e1 / ssum;

    float lad[10];
#pragma unroll
    for (int f = 0; f < NBANDS; ++f) {
        float part = w0 * sigd[n0 * NBANDS + f] + w1 * sigd[n1 * NBANDS + f];
        part = wave_sum64(part);
        lad[f] = logf(part <= 1e-9f ? 1e-9f : part);
    }

    float las[10];
#pragma unroll
    for (int f = 0; f < NBANDS; ++f) las[f] = 0.f;
    const int* mrow = mask + (size_t)pg * NSURF;
#pragma unroll
    for (int s = 0; s < NSURF; ++s) {
        float mv = (float)mrow[s];
#pragma unroll
        for (int f = 0; f < NBANDS; ++f) las[f] += mv * logr[s * NBANDS + f];
    }

    int dly = delays[pg];
    float g = 1.f / fmaxf((float)dly / 48.f, 1.f);
    float gsc = g * 16384.f;   // fold 2^14 MFMA-denorm-guard scale

    _Float16* row = A + (size_t)p * 2048;
#pragma unroll
    for (int i = 0; i < 8; ++i) {
        int q = i * 64 + lane;
        float la = 0.f, ph = 0.f;
#pragma unroll
        for (int f = 0; f < NBANDS; ++f) {
            la += las[f] * SI[f * NFREQ + q] + lad[f] * DI[f * NFREQ + q];
            ph += las[f] * PST[f * NFREQ + q] + lad[f] * PDT[f * NFREQ + q];
        }
        float M = gsc * expf(la);
        float sn, cs;
        sincosf(ph, &sn, &cs);
        float av = M * cs, bv = M * sn;
        _Float16 ah = (_Float16)av, bh = (_Float16)bv;
        row[q]          = ah;
        row[512 + q]    = bh;
        row[1024 + q]   = (_Float16)(av - (float)ah);
        row[1536 + q]   = (_Float16)(bv - (float)bh);
    }
}

// ---------------- k2: f16 MFMA GEMM [m x 3072-limb-K] * WT + scatter into rir ----------------
// C = Ahi*Whi + Alo*Whi + Ahi*Wlo  (panels 0,1,2), descale 2^-28 in epilogue.
#define KSTEPS 96
__global__ __launch_bounds__(256) void k2_gemm_scatter(
    const _Float16* __restrict__ A, const _Float16* __restrict__ WT,
    const int* __restrict__ delays, float* __restrict__ rir, int chunkStart)
{
    __shared__ __align__(16) char smem[16384];   // As 8KB | Bs 8KB  ([128 rows][32 f16])
    char* Asm = smem;
    char* Bsm = smem + 8192;

    int nwg = gridDim.x, cpx = nwg >> 3, bid = blockIdx.x;
    int swz = (bid & 7) * cpx + (bid >> 3);       // XCD-aware (grid % 8 == 0)
    int rowTile = swz >> 3, colTile = swz & 7;
    int p0 = rowTile * 128, t0 = colTile * 128;

    int tid = threadIdx.x, lane = tid & 63, wid = tid >> 6;
    int wr = wid >> 1, wc = wid & 1;

    f32x4 acc[4][4];
#pragma unroll
    for (int i = 0; i < 4; ++i)
#pragma unroll
        for (int j = 0; j < 4; ++j) acc[i][j] = (f32x4){0.f, 0.f, 0.f, 0.f};

    int d0 = tid * 16;                       // linear staging dest byte (it=0)
    char* ldsA0 = Asm + (tid & ~63) * 16;    // wave-uniform LDS base (+lane*16 implicit)
    char* ldsB0 = Bsm + (tid & ~63) * 16;
    int li = lane & 15, ksl = lane >> 4;

    for (int ks = 0; ks < KSTEPS; ++ks) {
        int panel = ks >> 5;
        int kk = (ks & 31) * 32;
        int aoff = ((panel == 1) ? 1024 : 0) + kk;
        const _Float16* wbase = WT + ((panel == 2) ? (1 << 20) : 0);
#pragma unroll
        for (int it = 0; it < 2; ++it) {
            int d = d0 + it * 4096;
            int row = d >> 6, inner = d & 63;
            const char* gA = (const char*)(A + (size_t)(p0 + row) * 2048 + aoff) + inner;
            const char* gB = (const char*)(wbase + (size_t)(t0 + row) * 1024 + kk) + inner;
            gload16(gA, ldsA0 + it * 4096);
            gload16(gB, ldsB0 + it * 4096);
        }
        __syncthreads();   // compiler emits vmcnt(0) before barrier -> tiles ready

        f16x8 af[4], bf[4];
#pragma unroll
        for (int mm = 0; mm < 4; ++mm)
            af[mm] = *(const f16x8*)(Asm + (wr * 64 + mm * 16 + li) * 64 + ksl * 16);
#pragma unroll
        for (int nn = 0; nn < 4; ++nn)
            bf[nn] = *(const f16x8*)(Bsm + (wc * 64 + nn * 16 + li) * 64 + ksl * 16);
#pragma unroll
        for (int mm = 0; mm < 4; ++mm)
#pragma unroll
            for (int nn = 0; nn < 4; ++nn)
                acc[mm][nn] = __builtin_amdgcn_mfma_f32_16x16x32_f16(af[mm], bf[nn], acc[mm][nn], 0, 0, 0);
        __syncthreads();   // protect LDS before next stage
    }

    const float dsc = 1.f / (16384.f * 16384.f);  // exact 2^-28
#pragma unroll
    for (int mm = 0; mm < 4; ++mm) {
        int prow = p0 + wr * 64 + mm * 16 + (lane >> 4) * 4;
#pragma unroll
        for (int r = 0; r < 4; ++r) {
            int pg = chunkStart + prow + r;
            int bi = pg >> 12;                    // 4096 paths per batch row
            int dly = delays[pg];
            float* rb = rir + (size_t)bi * RIR_LEN + dly;
#pragma unroll
            for (int nn = 0; nn < 4; ++nn) {
                int t = t0 + wc * 64 + nn * 16 + li;
                if (t < FILT_LEN) atomicAdd(&rb[t], acc[mm][nn][r] * dsc);
            }
        }
    }
}

// ---------------- k3: 'same' cross-correlation with source kernel ----------------
#define SEG 1024
__global__ __launch_bounds__(256) void k3_conv(
    const float* __restrict__ rir, const float* __restrict__ kern, float* __restrict__ out)
{
    __shared__ float rs[SEG + FILT_LEN - 1 + 8];
    __shared__ float ks[FILT_LEN];
    int b = blockIdx.y;
    int t0 = blockIdx.x * SEG;
    for (int i = threadIdx.x; i < FILT_LEN; i += 256) ks[i] = kern[i];
    for (int i = threadIdx.x; i < SEG + FILT_LEN - 1 + 8; i += 256) {
        int t = t0 - 511 + i;
        rs[i] = (i < SEG + FILT_LEN - 1 && t >= 0 && t < RIR_LEN)
                    ? rir[(size_t)b * RIR_LEN + t] : 0.f;
    }
    __syncthreads();

    int base = threadIdx.x * 4;
    float a0 = 0.f, a1 = 0.f, a2 = 0.f, a3 = 0.f;
    float w0 = rs[base], w1 = rs[base + 1], w2 = rs[base + 2], w3 = rs[base + 3];
    for (int k = 0; k < FILT_LEN; ++k) {
        float kv = ks[k];
        a0 = fmaf(kv, w0, a0);
        a1 = fmaf(kv, w1, a1);
        a2 = fmaf(kv, w2, a2);
        a3 = fmaf(kv, w3, a3);
        w0 = w1; w1 = w2; w2 = w3; w3 = rs[base + k + 4];
    }
    int t = t0 + base;
    size_t ob = (size_t)b * RIR_LEN;
    if (t + 0 < RIR_LEN) out[ob + t + 0] = a0;
    if (t + 1 < RIR_LEN) out[ob + t + 1] = a1;
    if (t + 2 < RIR_LEN) out[ob + t + 2] = a2;
    if (t + 3 < RIR_LEN) out[ob + t + 3] = a3;
}

extern "C" void kernel_launch(void* const* d_in, const int* in_sizes, int n_in,
                              void* d_out, int out_size, void* d_ws, size_t ws_size,
                              hipStream_t stream)
{
    const float* surface_params = (const float*)d_in[0];
    const float* dir_params     = (const float*)d_in[1];
    const float* path_dirs      = (const float*)d_in[2];
    const float* source_kernel  = (const float*)d_in[3];
    const float* surf_interp    = (const float*)d_in[4];
    const float* dir_interp     = (const float*)d_in[5];
    const float* fib_points     = (const float*)d_in[6];
    const int*   mask           = (const int*)d_in[7];
    const int*   delays         = (const int*)d_in[8];
    float* out = (float*)d_out;
    char*  ws  = (char*)d_ws;

    float*     rir  = (float*)(ws + WS_RIR);
    _Float16*  WT   = (_Float16*)(ws + WS_WT);       // [0]=hi, [1<<20]=lo
    double*    twc  = (double*)(ws + WS_TWC);
    double*    tws  = (double*)(ws + WS_TWS);
    float*     logr = (float*)(ws + WS_LOGR);
    float*     sigd = (float*)(ws + WS_SIGD);
    float*     PST  = (float*)(ws + WS_PST);
    float*     PDT  = (float*)(ws + WS_PDT);
    double*    Gs   = (double*)(ws + WS_GS);
    double*    Gd   = (double*)(ws + WS_GD);
    _Float16*  A    = (_Float16*)(ws + WS_A);

    // adaptive chunking of the A intermediate (4KB per path) against ws_size
    size_t abCap = (ws_size > WS_A) ? (ws_size - WS_A) : 0;
    long long cm = (long long)((abCap / 4096) & ~(size_t)127);
    if (cm > NPATH) cm = NPATH;
    if (cm < 128)   cm = 128;
    int chunkM = (int)cm;

    hipMemsetAsync(rir, 0, (size_t)8 * RIR_LEN * sizeof(float), stream);

    k0a_tables<<<16, 256, 0, stream>>>(surface_params, dir_params, twc, tws, logr, sigd);
    k0b_G     <<<20, 256, 0, stream>>>(surf_interp, dir_interp, twc, Gs, Gd);
    k0c_PSPD  <<<20, 256, 0, stream>>>(tws, Gs, Gd, PST, PDT);
    k0d_W     <<<4096, 256, 0, stream>>>(twc, tws, WT, WT + (1 << 20));

    for (int cs = 0; cs < NPATH; cs += chunkM) {
        int m = NPATH - cs;
        if (m > chunkM) m = chunkM;
        k1_ab<<<m / 4, 256, 0, stream>>>(path_dirs, fib_points, mask, delays,
                                         logr, sigd, surf_interp, dir_interp,
                                         PST, PDT, A, cs, m);
        k2_gemm_scatter<<<(m / 128) * 8, 256, 0, stream>>>(A, WT, delays, rir, cs);
    }

    dim3 g3((RIR_LEN + SEG - 1) / SEG, 8);
    k3_conv<<<g3, 256, 0, stream>>>(rir, source_kernel, out);
}

// Round 3
// 670.715 us; speedup vs baseline: 2.3005x; 1.0216x over previous
//
#include <hip/hip_runtime.h>
#include <math.h>

#define N_FFTC    1023
#define NFREQ     512
#define NBANDS    10
#define NPATH     32768
#define NSURF     16
#define NDIR      128
#define RIR_LEN   96000
#define FILT_LEN  1023
#define TWO_PI_D  6.283185307179586476925286766559

typedef _Float16 f16x8 __attribute__((ext_vector_type(8)));
typedef float    f32x4 __attribute__((ext_vector_type(4)));

#define AS1 __attribute__((address_space(1)))
#define AS3 __attribute__((address_space(3)))
__device__ __forceinline__ void gload16(const void* g, void* l) {
    __builtin_amdgcn_global_load_lds((const AS1 void*)g, (AS3 void*)l, 16, 0, 0);
}

// ---- ws layout (bytes) ----
#define WS_RIR    0UL            // f32 [8][96000]                 3,072,000
#define WS_WT     3072000UL      // f16 [2][1024][1024] hi|lo      4,194,304
#define WS_TWC    7266304UL      // dbl [1023]
#define WS_TWS    7274496UL      // dbl [1023]
#define WS_LOGR   7282688UL      // f32 [16][10]
#define WS_SIGD   7283456UL      // f32 [128][10]
#define WS_PST    7288576UL      // f32 [10][512]
#define WS_PDT    7309056UL      // f32 [10][512]
#define WS_GS     7329536UL      // dbl [10][512]
#define WS_GD     7370496UL      // dbl [10][512]
#define WS_A      7411712UL      // f16 [chunkM][2048]  (hi 1024 | lo 1024), 4KB/path

// ---------------- k0a: twiddles (fp64) + log_refl + sig_dir ----------------
__global__ void k0a_tables(const float* __restrict__ sp, const float* __restrict__ dp,
                           double* __restrict__ twc, double* __restrict__ tws,
                           float* __restrict__ logr, float* __restrict__ sigd)
{
    int idx = blockIdx.x * 256 + threadIdx.x;
    if (idx < 1023) {
        double ang = TWO_PI_D * (double)idx / 1023.0;
        twc[idx] = cos(ang);
        tws[idx] = sin(ang);
    } else if (idx >= 1024 && idx < 1024 + NSURF * NBANDS) {
        int i = idx - 1024;
        float s = 1.f / (1.f + expf(-sp[i]));
        logr[i] = logf(s <= 1e-9f ? 1e-9f : s);
    } else if (idx >= 2048 && idx < 2048 + NDIR * NBANDS) {
        int i = idx - 2048;
        sigd[i] = 1.f / (1.f + expf(-dp[i]));
    }
}

// ---------------- k0b: G[f][n] = sum_m c_m cos(2pi m n/N) * I[f][m] ----------------
__global__ void k0b_G(const float* __restrict__ SI, const float* __restrict__ DI,
                      const double* __restrict__ twc,
                      double* __restrict__ Gs, double* __restrict__ Gd)
{
    int idx = blockIdx.x * 256 + threadIdx.x;
    if (idx >= NBANDS * NFREQ) return;
    int f = idx >> 9, n = idx & 511;
    double gs = 0.0, gd = 0.0;
    for (int m = 0; m < NFREQ; ++m) {
        double c = (m == 0) ? 1.0 : 2.0;
        double t = c * twc[(m * n) % 1023];
        gs += t * (double)SI[f * NFREQ + m];
        gd += t * (double)DI[f * NFREQ + m];
    }
    Gs[idx] = gs;
    Gd[idx] = gd;
}

// ---------------- k0c: PS_T[f][k] = -(2/N) sum_{n=1}^{511} sin(2pi k n/N) G[f][n] ----------------
__global__ void k0c_PSPD(const double* __restrict__ tws,
                         const double* __restrict__ Gs, const double* __restrict__ Gd,
                         float* __restrict__ PST, float* __restrict__ PDT)
{
    int idx = blockIdx.x * 256 + threadIdx.x;
    if (idx >= NBANDS * NFREQ) return;
    int f = idx >> 9, k = idx & 511;
    double ps = 0.0, pd_ = 0.0;
    for (int n = 1; n < 512; ++n) {
        double s = tws[(k * n) % 1023];
        ps  += s * Gs[f * NFREQ + n];
        pd_ += s * Gd[f * NFREQ + n];
    }
    double sc = -2.0 / 1023.0;
    PST[idx] = (float)(sc * ps);
    PDT[idx] = (float)(sc * pd_);
}

// ---------------- k0d: WT[t][k] synthesis matrix (transposed), f16 limbs, x2^14 ----------------
__global__ void k0d_W(const double* __restrict__ twc, const double* __restrict__ tws,
                      _Float16* __restrict__ WThi, _Float16* __restrict__ WTlo)
{
    int idx = blockIdx.x * 256 + threadIdx.x;   // 1024*1024 over [t][k]
    int t = idx >> 10, k = idx & 1023;
    double v = 0.0;
    if (t < 1023) {
        if (k < 512) v = (((k == 0) ? 1.0 : 2.0) / 1023.0) * twc[(k * t) % 1023];
        else         v = (2.0 / 1023.0) * tws[((k - 512) * t) % 1023];
    }
    float vf = (float)(v * 16384.0);
    _Float16 h = (_Float16)vf;
    WThi[idx] = h;
    WTlo[idx] = (_Float16)(vf - (float)h);
}

__device__ __forceinline__ float wave_sum64(float v) {
#pragma unroll
    for (int m = 1; m < 64; m <<= 1) v += __shfl_xor(v, m, 64);
    return v;
}
__device__ __forceinline__ float wave_max64(float v) {
#pragma unroll
    for (int m = 1; m < 64; m <<= 1) v = fmaxf(v, __shfl_xor(v, m, 64));
    return v;
}

// ---------------- k1: per-path a,b limbs; LDS-staged transpose -> coalesced 16B stores ----------------
__global__ __launch_bounds__(256) void k1_ab(
    const float* __restrict__ path_dirs, const float* __restrict__ fib,
    const int* __restrict__ mask, const int* __restrict__ delays,
    const float* __restrict__ logr, const float* __restrict__ sigd,
    const float* __restrict__ SI, const float* __restrict__ DI,
    const float* __restrict__ PST, const float* __restrict__ PDT,
    _Float16* __restrict__ A, int chunkStart, int m)
{
    __shared__ _Float16 stg[4][2048];
    int wave = threadIdx.x >> 6, lane = threadIdx.x & 63;
    int p = blockIdx.x * 4 + wave;
    if (p >= m) return;
    int pg = chunkStart + p;

    float dx = path_dirs[pg * 3 + 0], dy = path_dirs[pg * 3 + 1], dz = path_dirs[pg * 3 + 2];
    float inv = 1.f / (sqrtf(dx * dx + dy * dy + dz * dz) + 1e-9f);
    dx *= inv; dy *= inv; dz *= inv;

    int n0 = lane, n1 = lane + 64;
    float l0 = 8.f * (dx * fib[n0 * 3] + dy * fib[n0 * 3 + 1] + dz * fib[n0 * 3 + 2]);
    float l1 = 8.f * (dx * fib[n1 * 3] + dy * fib[n1 * 3 + 1] + dz * fib[n1 * 3 + 2]);
    float mx = wave_max64(fmaxf(l0, l1));
    float e0 = expf(l0 - mx), e1 = expf(l1 - mx);
    float ssum = wave_sum64(e0 + e1);
    float w0 = e0 / ssum, w1 = e1 / ssum;

    float lad[10];
#pragma unroll
    for (int f = 0; f < NBANDS; ++f) {
        float part = w0 * sigd[n0 * NBANDS + f] + w1 * sigd[n1 * NBANDS + f];
        part = wave_sum64(part);
        lad[f] = logf(part <= 1e-9f ? 1e-9f : part);
    }

    float las[10];
#pragma unroll
    for (int f = 0; f < NBANDS; ++f) las[f] = 0.f;
    const int* mrow = mask + (size_t)pg * NSURF;
#pragma unroll
    for (int s = 0; s < NSURF; ++s) {
        float mv = (float)mrow[s];
#pragma unroll
        for (int f = 0; f < NBANDS; ++f) las[f] += mv * logr[s * NBANDS + f];
    }

    int dly = delays[pg];
    float g = 1.f / fmaxf((float)dly / 48.f, 1.f);
    float gsc = g * 16384.f;   // fold 2^14 MFMA-denorm-guard scale

#pragma unroll
    for (int i = 0; i < 8; ++i) {
        int q = i * 64 + lane;
        float la = 0.f, ph = 0.f;
#pragma unroll
        for (int f = 0; f < NBANDS; ++f) {
            la += las[f] * SI[f * NFREQ + q] + lad[f] * DI[f * NFREQ + q];
            ph += las[f] * PST[f * NFREQ + q] + lad[f] * PDT[f * NFREQ + q];
        }
        float M = gsc * expf(la);
        float sn, cs;
        sincosf(ph, &sn, &cs);
        float av = M * cs, bv = M * sn;
        _Float16 ah = (_Float16)av, bh = (_Float16)bv;
        stg[wave][q]        = ah;
        stg[wave][512 + q]  = bh;
        stg[wave][1024 + q] = (_Float16)(av - (float)ah);
        stg[wave][1536 + q] = (_Float16)(bv - (float)bh);
    }

    // coalesced writeout: 4 x 16B per lane (1KB per wave-instr)
    _Float16* row = A + (size_t)p * 2048;
#pragma unroll
    for (int seg = 0; seg < 4; ++seg) {
        f16x8 v = *(const f16x8*)&stg[wave][seg * 512 + lane * 8];
        *(f16x8*)(row + seg * 512 + lane * 8) = v;
    }
}

// ---------------- k2: f16 MFMA GEMM [m x 3072-limb-K] * WT + scatter into rir ----------------
// C = Ahi*Whi + Alo*Whi + Ahi*Wlo  (panels 0,1,2), descale 2^-28 in epilogue.
// LDS tiles XOR-swizzled (slot ^= (row>>1)&3): linear dest + pre-swizzled global src + swizzled read.
#define KSTEPS 96
__global__ __launch_bounds__(256) void k2_gemm_scatter(
    const _Float16* __restrict__ A, const _Float16* __restrict__ WT,
    const int* __restrict__ delays, float* __restrict__ rir, int chunkStart)
{
    __shared__ __align__(16) char smem[16384];   // As 8KB | Bs 8KB  ([128 rows][32 f16])
    char* Asm = smem;
    char* Bsm = smem + 8192;

    int nwg = gridDim.x, cpx = nwg >> 3, bid = blockIdx.x;
    int swz = (bid & 7) * cpx + (bid >> 3);       // XCD-aware (grid % 8 == 0)
    int rowTile = swz >> 3, colTile = swz & 7;
    int p0 = rowTile * 128, t0 = colTile * 128;

    int tid = threadIdx.x, lane = tid & 63, wid = tid >> 6;
    int wr = wid >> 1, wc = wid & 1;

    f32x4 acc[4][4];
#pragma unroll
    for (int i = 0; i < 4; ++i)
#pragma unroll
        for (int j = 0; j < 4; ++j) acc[i][j] = (f32x4){0.f, 0.f, 0.f, 0.f};

    int d0 = tid * 16;                       // linear staging dest byte (it=0)
    char* ldsA0 = Asm + (tid & ~63) * 16;    // wave-uniform LDS base (+lane*16 implicit)
    char* ldsB0 = Bsm + (tid & ~63) * 16;
    int li = lane & 15, ksl = lane >> 4;
    int sws = (((li >> 1) & 3) ^ ksl) << 4;  // swizzled k-slot byte offset for fragment reads

    for (int ks = 0; ks < KSTEPS; ++ks) {
        int panel = ks >> 5;
        int kk = (ks & 31) * 32;
        int aoff = ((panel == 1) ? 1024 : 0) + kk;
        const _Float16* wbase = WT + ((panel == 2) ? (1 << 20) : 0);
#pragma unroll
        for (int it = 0; it < 2; ++it) {
            int d = d0 + it * 4096;
            int row = d >> 6;
            int inner = (d & 63) ^ (((d >> 7) & 3) << 4);   // pre-swizzled source slot
            const char* gA = (const char*)(A + (size_t)(p0 + row) * 2048 + aoff) + inner;
            const char* gB = (const char*)(wbase + (size_t)(t0 + row) * 1024 + kk) + inner;
            gload16(gA, ldsA0 + it * 4096);
            gload16(gB, ldsB0 + it * 4096);
        }
        __syncthreads();   // vmcnt(0) drained before barrier -> tiles ready

        f16x8 af[4], bf[4];
#pragma unroll
        for (int mm = 0; mm < 4; ++mm)
            af[mm] = *(const f16x8*)(Asm + (wr * 64 + mm * 16 + li) * 64 + sws);
#pragma unroll
        for (int nn = 0; nn < 4; ++nn)
            bf[nn] = *(const f16x8*)(Bsm + (wc * 64 + nn * 16 + li) * 64 + sws);
#pragma unroll
        for (int mm = 0; mm < 4; ++mm)
#pragma unroll
            for (int nn = 0; nn < 4; ++nn)
                acc[mm][nn] = __builtin_amdgcn_mfma_f32_16x16x32_f16(af[mm], bf[nn], acc[mm][nn], 0, 0, 0);
        __syncthreads();   // protect LDS before next stage
    }

    const float dsc = 1.f / (16384.f * 16384.f);  // exact 2^-28
#pragma unroll
    for (int mm = 0; mm < 4; ++mm) {
        int prow = p0 + wr * 64 + mm * 16 + (lane >> 4) * 4;
#pragma unroll
        for (int r = 0; r < 4; ++r) {
            int pg = chunkStart + prow + r;
            int bi = pg >> 12;                    // 4096 paths per batch row
            int dly = delays[pg];
            float* rb = rir + (size_t)bi * RIR_LEN + dly;
#pragma unroll
            for (int nn = 0; nn < 4; ++nn) {
                int t = t0 + wc * 64 + nn * 16 + li;
                if (t < FILT_LEN) atomicAdd(&rb[t], acc[mm][nn][r] * dsc);
            }
        }
    }
}

// ---------------- k3: 'same' cross-correlation; 8 out/thread, skewed LDS ----------------
#define SEG 2048
#define SK(i) ((i) + ((i) >> 5))
__global__ __launch_bounds__(256) void k3_conv(
    const float* __restrict__ rir, const float* __restrict__ kern, float* __restrict__ out)
{
    __shared__ float rs[3184];     // skewed: logical 2048+1022+8
    __shared__ float ks[FILT_LEN];
    int b = blockIdx.y;
    int t0 = blockIdx.x * SEG;
    for (int i = threadIdx.x; i < FILT_LEN; i += 256) ks[i] = kern[i];
    for (int i = threadIdx.x; i < SEG + FILT_LEN - 1 + 8; i += 256) {
        int t = t0 - 511 + i;
        rs[SK(i)] = (t >= 0 && t < RIR_LEN) ? rir[(size_t)b * RIR_LEN + t] : 0.f;
    }
    __syncthreads();

    int base = threadIdx.x * 8;
    float a0 = 0.f, a1 = 0.f, a2 = 0.f, a3 = 0.f, a4 = 0.f, a5 = 0.f, a6 = 0.f, a7 = 0.f;
    float w0 = rs[SK(base + 0)], w1 = rs[SK(base + 1)], w2 = rs[SK(base + 2)], w3 = rs[SK(base + 3)];
    float w4 = rs[SK(base + 4)], w5 = rs[SK(base + 5)], w6 = rs[SK(base + 6)], w7 = rs[SK(base + 7)];
#pragma unroll 8
    for (int k = 0; k < FILT_LEN; ++k) {
        float kv = ks[k];
        a0 = fmaf(kv, w0, a0); a1 = fmaf(kv, w1, a1);
        a2 = fmaf(kv, w2, a2); a3 = fmaf(kv, w3, a3);
        a4 = fmaf(kv, w4, a4); a5 = fmaf(kv, w5, a5);
        a6 = fmaf(kv, w6, a6); a7 = fmaf(kv, w7, a7);
        w0 = w1; w1 = w2; w2 = w3; w3 = w4; w4 = w5; w5 = w6; w6 = w7;
        w7 = rs[SK(base + k + 8)];
    }
    int t = t0 + base;
    size_t ob = (size_t)b * RIR_LEN;
    if (t + 7 < RIR_LEN) {
        float4 v0 = {a0, a1, a2, a3}, v1 = {a4, a5, a6, a7};
        *(float4*)&out[ob + t]     = v0;
        *(float4*)&out[ob + t + 4] = v1;
    } else {
        float av[8] = {a0, a1, a2, a3, a4, a5, a6, a7};
        for (int j = 0; j < 8; ++j)
            if (t + j < RIR_LEN) out[ob + t + j] = av[j];
    }
}

extern "C" void kernel_launch(void* const* d_in, const int* in_sizes, int n_in,
                              void* d_out, int out_size, void* d_ws, size_t ws_size,
                              hipStream_t stream)
{
    const float* surface_params = (const float*)d_in[0];
    const float* dir_params     = (const float*)d_in[1];
    const float* path_dirs      = (const float*)d_in[2];
    const float* source_kernel  = (const float*)d_in[3];
    const float* surf_interp    = (const float*)d_in[4];
    const float* dir_interp     = (const float*)d_in[5];
    const float* fib_points     = (const float*)d_in[6];
    const int*   mask           = (const int*)d_in[7];
    const int*   delays         = (const int*)d_in[8];
    float* out = (float*)d_out;
    char*  ws  = (char*)d_ws;

    float*     rir  = (float*)(ws + WS_RIR);
    _Float16*  WT   = (_Float16*)(ws + WS_WT);       // [0]=hi, [1<<20]=lo
    double*    twc  = (double*)(ws + WS_TWC);
    double*    tws  = (double*)(ws + WS_TWS);
    float*     logr = (float*)(ws + WS_LOGR);
    float*     sigd = (float*)(ws + WS_SIGD);
    float*     PST  = (float*)(ws + WS_PST);
    float*     PDT  = (float*)(ws + WS_PDT);
    double*    Gs   = (double*)(ws + WS_GS);
    double*    Gd   = (double*)(ws + WS_GD);
    _Float16*  A    = (_Float16*)(ws + WS_A);

    // adaptive chunking of the A intermediate (4KB per path) against ws_size
    size_t abCap = (ws_size > WS_A) ? (ws_size - WS_A) : 0;
    long long cm = (long long)((abCap / 4096) & ~(size_t)127);
    if (cm > NPATH) cm = NPATH;
    if (cm < 128)   cm = 128;
    int chunkM = (int)cm;

    hipMemsetAsync(rir, 0, (size_t)8 * RIR_LEN * sizeof(float), stream);

    k0a_tables<<<16, 256, 0, stream>>>(surface_params, dir_params, twc, tws, logr, sigd);
    k0b_G     <<<20, 256, 0, stream>>>(surf_interp, dir_interp, twc, Gs, Gd);
    k0c_PSPD  <<<20, 256, 0, stream>>>(tws, Gs, Gd, PST, PDT);
    k0d_W     <<<4096, 256, 0, stream>>>(twc, tws, WT, WT + (1 << 20));

    for (int cs = 0; cs < NPATH; cs += chunkM) {
        int m = NPATH - cs;
        if (m > chunkM) m = chunkM;
        k1_ab<<<m / 4, 256, 0, stream>>>(path_dirs, fib_points, mask, delays,
                                         logr, sigd, surf_interp, dir_interp,
                                         PST, PDT, A, cs, m);
        k2_gemm_scatter<<<(m / 128) * 8, 256, 0, stream>>>(A, WT, delays, rir, cs);
    }

    dim3 g3((RIR_LEN + SEG - 1) / SEG, 8);
    k3_conv<<<g3, 256, 0, stream>>>(rir, source_kernel, out);
}